// Round 1
// baseline (876.690 us; speedup 1.0000x reference)
//
#include <hip/hip_runtime.h>

#define B_  2
#define NH  16
#define S_  2048
#define D_  128
#define HID 2048
#define BS  4096

typedef _Float16 half_t;
typedef _Float16 f16x8 __attribute__((ext_vector_type(8)));
typedef _Float16 f16x4_t __attribute__((ext_vector_type(4)));
typedef float f32x4 __attribute__((ext_vector_type(4)));

// ---------------- fp32 -> fp16 convert ----------------
__global__ __launch_bounds__(256) void cvt_kernel(const float* __restrict__ src,
                                                  half_t* __restrict__ dst, int n) {
    int i = (blockIdx.x * 256 + threadIdx.x) * 4;
    if (i >= n) return;
    float4 v = *(const float4*)(src + i);
    f16x4_t h;
    h[0] = (half_t)v.x; h[1] = (half_t)v.y; h[2] = (half_t)v.z; h[3] = (half_t)v.w;
    *(f16x4_t*)(dst + i) = h;
}

// ---------------- fused QKV GEMM + RoPE ----------------
// C[m][n] = sum_k X[m][k] * W[n][k]; block tile 64(m) x 128(n=one head), K-step 32.
// z = 0:Q (RoPE), 1:K (RoPE), 2:V (store transposed (b,h,d,s))
__global__ __launch_bounds__(256) void qkv_gemm(
    const half_t* __restrict__ xb,
    const half_t* __restrict__ wqb, const half_t* __restrict__ wkb, const half_t* __restrict__ wvb,
    const float* __restrict__ bq, const float* __restrict__ bk, const float* __restrict__ bv,
    const float* __restrict__ cosp, const float* __restrict__ sinp,
    half_t* __restrict__ qo, half_t* __restrict__ ko, half_t* __restrict__ vto)
{
    __shared__ __align__(16) half_t xs[64 * 32];
    __shared__ __align__(16) half_t wsh[128 * 32];
    const int m0 = blockIdx.x * 64;
    const int n0 = blockIdx.y * 128;
    const int z  = blockIdx.z;
    const half_t* wb   = (z == 0) ? wqb : (z == 1) ? wkb : wvb;
    const float*  bias = (z == 0) ? bq  : (z == 1) ? bk  : bv;
    const int tid = threadIdx.x;
    const int wave = tid >> 6, lane = tid & 63;
    const int quad = lane >> 4, lrow = lane & 15;

    f32x4 acc[8] = {};

    const half_t* xg  = xb + (size_t)(m0 + (tid >> 2)) * HID + (tid & 3) * 8;
    const half_t* wg0 = wb + (size_t)(n0 + (tid >> 2)) * HID + (tid & 3) * 8;
    const half_t* wg1 = wg0 + (size_t)64 * HID;

    for (int k0 = 0; k0 < HID; k0 += 32) {
        f16x8 xv  = *(const f16x8*)(xg + k0);
        f16x8 wv0 = *(const f16x8*)(wg0 + k0);
        f16x8 wv1 = *(const f16x8*)(wg1 + k0);
        __syncthreads();
        *(f16x8*)&xs[tid * 8] = xv;
        *(f16x8*)&wsh[tid * 8] = wv0;
        *(f16x8*)&wsh[2048 + tid * 8] = wv1;
        __syncthreads();
        f16x8 af = *(const f16x8*)&xs[(wave * 16 + lrow) * 32 + quad * 8];
#pragma unroll
        for (int t = 0; t < 8; t++) {
            f16x8 bff = *(const f16x8*)&wsh[(t * 16 + lrow) * 32 + quad * 8];
            acc[t] = __builtin_amdgcn_mfma_f32_16x16x32_f16(af, bff, acc[t], 0, 0, 0);
        }
    }

    const int head = blockIdx.y;  // N-tile width == D
    float bs_[8];
#pragma unroll
    for (int t = 0; t < 8; t++) bs_[t] = bias[n0 + t * 16 + lrow];
    const int mbase = m0 + wave * 16 + quad * 4;
#pragma unroll
    for (int r = 0; r < 4; r++) {
        const int m  = mbase + r;
        const int b  = m >> 11;        // / S_
        const int st = m & (S_ - 1);
        float res[8];
#pragma unroll
        for (int t = 0; t < 8; t++) res[t] = acc[t][r] + bs_[t];
        if (z < 2) {
            // RoPE: d<64: q*cos - q[d+64]*sin ; d>=64: q*cos + q[d-64]*sin
#pragma unroll
            for (int t = 0; t < 4; t++) {
                const int dlo = t * 16 + lrow;
                const int dhi = dlo + 64;
                float cl = cosp[st * D_ + dlo], sl = sinp[st * D_ + dlo];
                float ch = cosp[st * D_ + dhi], sh = sinp[st * D_ + dhi];
                float lo = res[t], hi = res[t + 4];
                res[t]     = lo * cl - hi * sl;
                res[t + 4] = hi * ch + lo * sh;
            }
            half_t* dst = (z == 0 ? qo : ko) + ((size_t)(b * NH + head) * S_ + st) * D_;
#pragma unroll
            for (int t = 0; t < 8; t++) dst[t * 16 + lrow] = (half_t)res[t];
        } else {
            half_t* dst = vto + (size_t)(b * NH + head) * D_ * S_;
#pragma unroll
            for (int t = 0; t < 8; t++) dst[(size_t)(t * 16 + lrow) * S_ + st] = (half_t)res[t];
        }
    }
}

// ---------------- attention: per (b, h, 16-row q-tile) ----------------
// Full 16 x 2048 score strip in LDS (64 KB), XOR chunk-swizzled; exact softmax.
__global__ __launch_bounds__(256) void attn_kernel(
    const half_t* __restrict__ qb, const half_t* __restrict__ kb,
    const half_t* __restrict__ vtb, half_t* __restrict__ ob)
{
    __shared__ __align__(16) half_t sc[16 * 2048];
    const int qt = blockIdx.x, head = blockIdx.y, b = blockIdx.z;
    const int bh = b * NH + head;
    const int tid = threadIdx.x;
    const int wave = tid >> 6, lane = tid & 63;
    const int quad = lane >> 4, lrow = lane & 15;
    const float scale = 0.08838834764831845f;  // 1/sqrt(128)

    // preload Q fragments (A-layout: m=lane&15, k=quad*8+j)
    const half_t* qrow = qb + ((size_t)bh * S_ + qt * 16 + lrow) * D_;
    f16x8 qf[4];
#pragma unroll
    for (int kc = 0; kc < 4; kc++) qf[kc] = *(const f16x8*)(qrow + kc * 32 + quad * 8);

    // phase 1: S = scale * Q K^T, swizzled store to LDS
    const half_t* kbase = kb + (size_t)bh * S_ * D_;
    for (int i = 0; i < 32; i++) {
        const int nt = wave + i * 4;
        f32x4 a = {};
#pragma unroll
        for (int kc = 0; kc < 4; kc++) {
            f16x8 bf = *(const f16x8*)(kbase + (size_t)(nt * 16 + lrow) * D_ + kc * 32 + quad * 8);
            a = __builtin_amdgcn_mfma_f32_16x16x32_f16(qf[kc], bf, a, 0, 0, 0);
        }
        const int chunk  = nt * 2 + (lrow >> 3);
        const int within = lrow & 7;
#pragma unroll
        for (int r = 0; r < 4; r++) {
            const int row = quad * 4 + r;
            sc[row * 2048 + ((chunk ^ row) * 8 + within)] = (half_t)(a[r] * scale);
        }
    }
    __syncthreads();

    // phase 2: softmax (16 threads per row), normalize P in LDS
    {
        const int row = tid >> 4, part = tid & 15;
        float mx = -1e30f;
        for (int i = 0; i < 16; i++) {
            const int c = part + i * 16;
            f16x8 v = *(const f16x8*)&sc[row * 2048 + (c ^ row) * 8];
#pragma unroll
            for (int j = 0; j < 8; j++) mx = fmaxf(mx, (float)v[j]);
        }
#pragma unroll
        for (int off = 1; off < 16; off <<= 1) mx = fmaxf(mx, __shfl_xor(mx, off, 16));
        float sum = 0.f;
        for (int i = 0; i < 16; i++) {
            const int c = part + i * 16;
            f16x8 v = *(const f16x8*)&sc[row * 2048 + (c ^ row) * 8];
#pragma unroll
            for (int j = 0; j < 8; j++) sum += __expf((float)v[j] - mx);
        }
#pragma unroll
        for (int off = 1; off < 16; off <<= 1) sum += __shfl_xor(sum, off, 16);
        const float rinv = 1.f / sum;
        for (int i = 0; i < 16; i++) {
            const int c = part + i * 16;
            f16x8 v = *(const f16x8*)&sc[row * 2048 + (c ^ row) * 8];
            f16x8 w;
#pragma unroll
            for (int j = 0; j < 8; j++) w[j] = (half_t)(__expf((float)v[j] - mx) * rinv);
            *(f16x8*)&sc[row * 2048 + (c ^ row) * 8] = w;
        }
    }
    __syncthreads();

    // phase 3: O = P V ; wave w covers d-tiles {2w, 2w+1}
    f32x4 oacc[2] = {};
    const half_t* vbase = vtb + (size_t)bh * D_ * S_;
    for (int kc = 0; kc < 64; kc++) {
        const int chunk = kc * 4 + quad;
        f16x8 pf = *(const f16x8*)&sc[lrow * 2048 + (chunk ^ lrow) * 8];
#pragma unroll
        for (int t = 0; t < 2; t++) {
            const int d = (wave * 2 + t) * 16 + lrow;
            f16x8 vf = *(const f16x8*)(vbase + (size_t)d * S_ + kc * 32 + quad * 8);
            oacc[t] = __builtin_amdgcn_mfma_f32_16x16x32_f16(pf, vf, oacc[t], 0, 0, 0);
        }
    }
#pragma unroll
    for (int t = 0; t < 2; t++) {
        const int d = (wave * 2 + t) * 16 + lrow;
#pragma unroll
        for (int r = 0; r < 4; r++) {
            const int strow = qt * 16 + quad * 4 + r;
            ob[((size_t)b * S_ + strow) * HID + head * D_ + d] = (half_t)oacc[t][r];
        }
    }
}

// ---------------- output projection: out = AttnOut @ Wo^T (fp32 out) ----------------
__global__ __launch_bounds__(256) void out_gemm(
    const half_t* __restrict__ ab, const half_t* __restrict__ wob, float* __restrict__ out)
{
    __shared__ __align__(16) half_t xs[64 * 32];
    __shared__ __align__(16) half_t wsh[128 * 32];
    const int m0 = blockIdx.x * 64;
    const int n0 = blockIdx.y * 128;
    const int tid = threadIdx.x;
    const int wave = tid >> 6, lane = tid & 63;
    const int quad = lane >> 4, lrow = lane & 15;

    f32x4 acc[8] = {};
    const half_t* xg  = ab  + (size_t)(m0 + (tid >> 2)) * HID + (tid & 3) * 8;
    const half_t* wg0 = wob + (size_t)(n0 + (tid >> 2)) * HID + (tid & 3) * 8;
    const half_t* wg1 = wg0 + (size_t)64 * HID;

    for (int k0 = 0; k0 < HID; k0 += 32) {
        f16x8 xv  = *(const f16x8*)(xg + k0);
        f16x8 wv0 = *(const f16x8*)(wg0 + k0);
        f16x8 wv1 = *(const f16x8*)(wg1 + k0);
        __syncthreads();
        *(f16x8*)&xs[tid * 8] = xv;
        *(f16x8*)&wsh[tid * 8] = wv0;
        *(f16x8*)&wsh[2048 + tid * 8] = wv1;
        __syncthreads();
        f16x8 af = *(const f16x8*)&xs[(wave * 16 + lrow) * 32 + quad * 8];
#pragma unroll
        for (int t = 0; t < 8; t++) {
            f16x8 bff = *(const f16x8*)&wsh[(t * 16 + lrow) * 32 + quad * 8];
            acc[t] = __builtin_amdgcn_mfma_f32_16x16x32_f16(af, bff, acc[t], 0, 0, 0);
        }
    }
    const int mbase = m0 + wave * 16 + quad * 4;
#pragma unroll
    for (int r = 0; r < 4; r++) {
        const int m = mbase + r;
#pragma unroll
        for (int t = 0; t < 8; t++)
            out[(size_t)m * HID + n0 + t * 16 + lrow] = acc[t][r];
    }
}

extern "C" void kernel_launch(void* const* d_in, const int* in_sizes, int n_in,
                              void* d_out, int out_size, void* d_ws, size_t ws_size,
                              hipStream_t stream)
{
    const float* x    = (const float*)d_in[0];
    const float* cosp = (const float*)d_in[1];
    const float* sinp = (const float*)d_in[2];
    const float* wq   = (const float*)d_in[3];
    const float* bq   = (const float*)d_in[4];
    const float* wk   = (const float*)d_in[5];
    const float* bk   = (const float*)d_in[6];
    const float* wv   = (const float*)d_in[7];
    const float* bv   = (const float*)d_in[8];
    const float* wo   = (const float*)d_in[9];
    float* out = (float*)d_out;

    half_t* w   = (half_t*)d_ws;
    half_t* xb  = w;                    // 8388608 el
    half_t* wqb = xb  + 8388608;        // 4194304
    half_t* wkb = wqb + 4194304;
    half_t* wvb = wkb + 4194304;
    half_t* wob = wvb + 4194304;
    half_t* qo  = wob + 4194304;        // 8388608 (b,h,s,d)
    half_t* ko  = qo  + 8388608;        // 8388608 (b,h,s,d)
    half_t* vto = ko  + 8388608;        // 8388608 (b,h,d,s)
    half_t* ob  = vto + 8388608;        // 8388608 (b,s,h*d)

    cvt_kernel<<<8192, 256, 0, stream>>>(x, xb, 8388608);
    cvt_kernel<<<4096, 256, 0, stream>>>(wq, wqb, 4194304);
    cvt_kernel<<<4096, 256, 0, stream>>>(wk, wkb, 4194304);
    cvt_kernel<<<4096, 256, 0, stream>>>(wv, wvb, 4194304);
    cvt_kernel<<<4096, 256, 0, stream>>>(wo, wob, 4194304);

    qkv_gemm<<<dim3(64, 16, 3), 256, 0, stream>>>(xb, wqb, wkb, wvb, bq, bk, bv,
                                                  cosp, sinp, qo, ko, vto);
    attn_kernel<<<dim3(128, 16, 2), 256, 0, stream>>>(qo, ko, vto, ob);
    out_gemm<<<dim3(64, 16), 256, 0, stream>>>(ob, wob, out);
}

// Round 2
// 583.247 us; speedup vs baseline: 1.5031x; 1.5031x over previous
//
#include <hip/hip_runtime.h>

#define B_  2
#define NH  16
#define S_  2048
#define D_  128
#define HID 2048

typedef _Float16 half_t;
typedef _Float16 f16x8 __attribute__((ext_vector_type(8)));
typedef _Float16 f16x4_t __attribute__((ext_vector_type(4)));
typedef float f32x4 __attribute__((ext_vector_type(4)));

// ---------------- fp32 -> fp16 convert ----------------
__global__ __launch_bounds__(256) void cvt_kernel(const float* __restrict__ src,
                                                  half_t* __restrict__ dst, int n) {
    int i = (blockIdx.x * 256 + threadIdx.x) * 4;
    if (i >= n) return;
    float4 v = *(const float4*)(src + i);
    f16x4_t h;
    h[0] = (half_t)v.x; h[1] = (half_t)v.y; h[2] = (half_t)v.z; h[3] = (half_t)v.w;
    *(f16x4_t*)(dst + i) = h;
}

// ---------------- fused QKV GEMM + RoPE ----------------
__global__ __launch_bounds__(256) void qkv_gemm(
    const half_t* __restrict__ xb,
    const half_t* __restrict__ wqb, const half_t* __restrict__ wkb, const half_t* __restrict__ wvb,
    const float* __restrict__ bq, const float* __restrict__ bk, const float* __restrict__ bv,
    const float* __restrict__ cosp, const float* __restrict__ sinp,
    half_t* __restrict__ qo, half_t* __restrict__ ko, half_t* __restrict__ vto)
{
    __shared__ __align__(16) half_t xs[64 * 32];
    __shared__ __align__(16) half_t wsh[128 * 32];
    const int m0 = blockIdx.x * 64;
    const int n0 = blockIdx.y * 128;
    const int z  = blockIdx.z;
    const half_t* wb   = (z == 0) ? wqb : (z == 1) ? wkb : wvb;
    const float*  bias = (z == 0) ? bq  : (z == 1) ? bk  : bv;
    const int tid = threadIdx.x;
    const int wave = tid >> 6, lane = tid & 63;
    const int quad = lane >> 4, lrow = lane & 15;

    f32x4 acc[8] = {};

    const half_t* xg  = xb + (size_t)(m0 + (tid >> 2)) * HID + (tid & 3) * 8;
    const half_t* wg0 = wb + (size_t)(n0 + (tid >> 2)) * HID + (tid & 3) * 8;
    const half_t* wg1 = wg0 + (size_t)64 * HID;

    for (int k0 = 0; k0 < HID; k0 += 32) {
        f16x8 xv  = *(const f16x8*)(xg + k0);
        f16x8 wv0 = *(const f16x8*)(wg0 + k0);
        f16x8 wv1 = *(const f16x8*)(wg1 + k0);
        __syncthreads();
        *(f16x8*)&xs[tid * 8] = xv;
        *(f16x8*)&wsh[tid * 8] = wv0;
        *(f16x8*)&wsh[2048 + tid * 8] = wv1;
        __syncthreads();
        f16x8 af = *(const f16x8*)&xs[(wave * 16 + lrow) * 32 + quad * 8];
#pragma unroll
        for (int t = 0; t < 8; t++) {
            f16x8 bff = *(const f16x8*)&wsh[(t * 16 + lrow) * 32 + quad * 8];
            acc[t] = __builtin_amdgcn_mfma_f32_16x16x32_f16(af, bff, acc[t], 0, 0, 0);
        }
    }

    const int head = blockIdx.y;
    float bs_[8];
#pragma unroll
    for (int t = 0; t < 8; t++) bs_[t] = bias[n0 + t * 16 + lrow];
    const int mbase = m0 + wave * 16 + quad * 4;
#pragma unroll
    for (int r = 0; r < 4; r++) {
        const int m  = mbase + r;
        const int b  = m >> 11;
        const int st = m & (S_ - 1);
        float res[8];
#pragma unroll
        for (int t = 0; t < 8; t++) res[t] = acc[t][r] + bs_[t];
        if (z < 2) {
#pragma unroll
            for (int t = 0; t < 4; t++) {
                const int dlo = t * 16 + lrow;
                const int dhi = dlo + 64;
                float cl = cosp[st * D_ + dlo], sl = sinp[st * D_ + dlo];
                float ch = cosp[st * D_ + dhi], sh = sinp[st * D_ + dhi];
                float lo = res[t], hi = res[t + 4];
                res[t]     = lo * cl - hi * sl;
                res[t + 4] = hi * ch + lo * sh;
            }
            half_t* dst = (z == 0 ? qo : ko) + ((size_t)(b * NH + head) * S_ + st) * D_;
#pragma unroll
            for (int t = 0; t < 8; t++) dst[t * 16 + lrow] = (half_t)res[t];
        } else {
            half_t* dst = vto + (size_t)(b * NH + head) * D_ * S_;
#pragma unroll
            for (int t = 0; t < 8; t++) dst[(size_t)(t * 16 + lrow) * S_ + st] = (half_t)res[t];
        }
    }
}

// ---------------- flash attention ----------------
// block: 256 thr (4 waves), Q-tile 128 rows (wave owns 32 = 2 m-tiles).
// K/V tiles of 64 staged in LDS; online softmax; P via LDS transpose.
#define KLD 136   // ks row stride (halfs): 68 dwords -> bank-uniform b128 reads
#define VLD 72    // vs / ps row stride (halfs): 36 dwords
__global__ __launch_bounds__(256, 3) void attn_kernel(
    const half_t* __restrict__ qb, const half_t* __restrict__ kb,
    const half_t* __restrict__ vtb, half_t* __restrict__ ob)
{
    __shared__ __align__(16) half_t ks[64 * KLD];        // 17408 B
    __shared__ __align__(16) half_t vs[128 * VLD];       // 18432 B
    __shared__ __align__(16) half_t ps[4 * 32 * VLD];    // 18432 B

    const int head = blockIdx.y, b = blockIdx.z;
    const int bh = b * NH + head;
    const int tid = threadIdx.x;
    const int wave = tid >> 6, lane = tid & 63;
    const int quad = lane >> 4, lrow = lane & 15;
    const float scale = 0.08838834764831845f;  // 1/sqrt(128)
    const int m0 = blockIdx.x * 128 + wave * 32;

    // Q fragments (A-layout), pre-scaled by 1/sqrt(d)
    f16x8 qf[2][4];
#pragma unroll
    for (int mt = 0; mt < 2; mt++) {
        const half_t* qrow = qb + ((size_t)bh * S_ + m0 + mt * 16 + lrow) * D_;
#pragma unroll
        for (int kc = 0; kc < 4; kc++) {
            f16x8 v = *(const f16x8*)(qrow + kc * 32 + quad * 8);
#pragma unroll
            for (int j = 0; j < 8; j++) v[j] = (half_t)((float)v[j] * scale);
            qf[mt][kc] = v;
        }
    }

    const half_t* kbase = kb + (size_t)bh * S_ * D_;
    const half_t* vbase = vtb + (size_t)bh * D_ * S_;
    const int krow = tid >> 2, kcol = (tid & 3) * 32;
    const int vrow = tid >> 1, vcol = (tid & 1) * 32;
    const int pbase = wave * 32 * VLD;

    float m_run[2][4], l_run[2][4];
#pragma unroll
    for (int mt = 0; mt < 2; mt++)
#pragma unroll
        for (int r = 0; r < 4; r++) { m_run[mt][r] = -1e30f; l_run[mt][r] = 0.f; }
    f32x4 o[2][8] = {};

    for (int kt = 0; kt < 32; kt++) {
        __syncthreads();
        {
            const half_t* gk = kbase + (size_t)(kt * 64 + krow) * D_ + kcol;
            const half_t* gv = vbase + (size_t)vrow * S_ + kt * 64 + vcol;
#pragma unroll
            for (int u = 0; u < 4; u++)
                *(f16x8*)&ks[krow * KLD + kcol + u * 8] = *(const f16x8*)(gk + u * 8);
#pragma unroll
            for (int u = 0; u < 4; u++)
                *(f16x8*)&vs[vrow * VLD + vcol + u * 8] = *(const f16x8*)(gv + u * 8);
        }
        __syncthreads();

        // S = Q K^T for this 64-col tile
        f32x4 s[2][4] = {};
#pragma unroll
        for (int nt = 0; nt < 4; nt++) {
#pragma unroll
            for (int kc = 0; kc < 4; kc++) {
                f16x8 kf = *(const f16x8*)&ks[(nt * 16 + lrow) * KLD + kc * 32 + quad * 8];
                s[0][nt] = __builtin_amdgcn_mfma_f32_16x16x32_f16(qf[0][kc], kf, s[0][nt], 0, 0, 0);
                s[1][nt] = __builtin_amdgcn_mfma_f32_16x16x32_f16(qf[1][kc], kf, s[1][nt], 0, 0, 0);
            }
        }

        // online softmax update + P write (wave-private ps region)
#pragma unroll
        for (int mt = 0; mt < 2; mt++) {
#pragma unroll
            for (int r = 0; r < 4; r++) {
                float mx = fmaxf(fmaxf(s[mt][0][r], s[mt][1][r]), fmaxf(s[mt][2][r], s[mt][3][r]));
#pragma unroll
                for (int off = 1; off < 16; off <<= 1) mx = fmaxf(mx, __shfl_xor(mx, off));
                const float mnew = fmaxf(m_run[mt][r], mx);
                const float alpha = __expf(m_run[mt][r] - mnew);
                m_run[mt][r] = mnew;
                float p0 = __expf(s[mt][0][r] - mnew);
                float p1 = __expf(s[mt][1][r] - mnew);
                float p2 = __expf(s[mt][2][r] - mnew);
                float p3 = __expf(s[mt][3][r] - mnew);
                float rs = (p0 + p1) + (p2 + p3);
#pragma unroll
                for (int off = 1; off < 16; off <<= 1) rs += __shfl_xor(rs, off);
                l_run[mt][r] = l_run[mt][r] * alpha + rs;
#pragma unroll
                for (int dt = 0; dt < 8; dt++) o[mt][dt][r] *= alpha;
                const int prow = pbase + (mt * 16 + quad * 4 + r) * VLD + lrow;
                ps[prow]      = (half_t)p0;
                ps[prow + 16] = (half_t)p1;
                ps[prow + 32] = (half_t)p2;
                ps[prow + 48] = (half_t)p3;
            }
        }

        // O += P V
#pragma unroll
        for (int kc2 = 0; kc2 < 2; kc2++) {
            f16x8 pf0 = *(const f16x8*)&ps[pbase + (lrow) * VLD + kc2 * 32 + quad * 8];
            f16x8 pf1 = *(const f16x8*)&ps[pbase + (16 + lrow) * VLD + kc2 * 32 + quad * 8];
#pragma unroll
            for (int dt = 0; dt < 8; dt++) {
                f16x8 vf = *(const f16x8*)&vs[(dt * 16 + lrow) * VLD + kc2 * 32 + quad * 8];
                o[0][dt] = __builtin_amdgcn_mfma_f32_16x16x32_f16(pf0, vf, o[0][dt], 0, 0, 0);
                o[1][dt] = __builtin_amdgcn_mfma_f32_16x16x32_f16(pf1, vf, o[1][dt], 0, 0, 0);
            }
        }
    }

    // epilogue: divide by l, store
#pragma unroll
    for (int mt = 0; mt < 2; mt++) {
        float rl[4];
#pragma unroll
        for (int r = 0; r < 4; r++) rl[r] = 1.f / l_run[mt][r];
#pragma unroll
        for (int dt = 0; dt < 8; dt++) {
            const int d = dt * 16 + lrow;
#pragma unroll
            for (int r = 0; r < 4; r++) {
                const int row = m0 + mt * 16 + quad * 4 + r;
                ob[((size_t)b * S_ + row) * HID + head * D_ + d] = (half_t)(o[mt][dt][r] * rl[r]);
            }
        }
    }
}

// ---------------- output projection ----------------
__global__ __launch_bounds__(256) void out_gemm(
    const half_t* __restrict__ ab, const half_t* __restrict__ wob, float* __restrict__ out)
{
    __shared__ __align__(16) half_t xs[64 * 32];
    __shared__ __align__(16) half_t wsh[128 * 32];
    const int m0 = blockIdx.x * 64;
    const int n0 = blockIdx.y * 128;
    const int tid = threadIdx.x;
    const int wave = tid >> 6, lane = tid & 63;
    const int quad = lane >> 4, lrow = lane & 15;

    f32x4 acc[8] = {};
    const half_t* xg  = ab  + (size_t)(m0 + (tid >> 2)) * HID + (tid & 3) * 8;
    const half_t* wg0 = wob + (size_t)(n0 + (tid >> 2)) * HID + (tid & 3) * 8;
    const half_t* wg1 = wg0 + (size_t)64 * HID;

    for (int k0 = 0; k0 < HID; k0 += 32) {
        f16x8 xv  = *(const f16x8*)(xg + k0);
        f16x8 wv0 = *(const f16x8*)(wg0 + k0);
        f16x8 wv1 = *(const f16x8*)(wg1 + k0);
        __syncthreads();
        *(f16x8*)&xs[tid * 8] = xv;
        *(f16x8*)&wsh[tid * 8] = wv0;
        *(f16x8*)&wsh[2048 + tid * 8] = wv1;
        __syncthreads();
        f16x8 af = *(const f16x8*)&xs[(wave * 16 + lrow) * 32 + quad * 8];
#pragma unroll
        for (int t = 0; t < 8; t++) {
            f16x8 bff = *(const f16x8*)&wsh[(t * 16 + lrow) * 32 + quad * 8];
            acc[t] = __builtin_amdgcn_mfma_f32_16x16x32_f16(af, bff, acc[t], 0, 0, 0);
        }
    }
    const int mbase = m0 + wave * 16 + quad * 4;
#pragma unroll
    for (int r = 0; r < 4; r++) {
        const int m = mbase + r;
#pragma unroll
        for (int t = 0; t < 8; t++)
            out[(size_t)m * HID + n0 + t * 16 + lrow] = acc[t][r];
    }
}

extern "C" void kernel_launch(void* const* d_in, const int* in_sizes, int n_in,
                              void* d_out, int out_size, void* d_ws, size_t ws_size,
                              hipStream_t stream)
{
    const float* x    = (const float*)d_in[0];
    const float* cosp = (const float*)d_in[1];
    const float* sinp = (const float*)d_in[2];
    const float* wq   = (const float*)d_in[3];
    const float* bq   = (const float*)d_in[4];
    const float* wk   = (const float*)d_in[5];
    const float* bk   = (const float*)d_in[6];
    const float* wv   = (const float*)d_in[7];
    const float* bv   = (const float*)d_in[8];
    const float* wo   = (const float*)d_in[9];
    float* out = (float*)d_out;

    half_t* w   = (half_t*)d_ws;
    half_t* xb  = w;
    half_t* wqb = xb  + 8388608;
    half_t* wkb = wqb + 4194304;
    half_t* wvb = wkb + 4194304;
    half_t* wob = wvb + 4194304;
    half_t* qo  = wob + 4194304;        // (b,h,s,d)
    half_t* ko  = qo  + 8388608;        // (b,h,s,d)
    half_t* vto = ko  + 8388608;        // (b,h,d,s)
    half_t* ob  = vto + 8388608;        // (b,s,h*d)

    cvt_kernel<<<8192, 256, 0, stream>>>(x, xb, 8388608);
    cvt_kernel<<<4096, 256, 0, stream>>>(wq, wqb, 4194304);
    cvt_kernel<<<4096, 256, 0, stream>>>(wk, wkb, 4194304);
    cvt_kernel<<<4096, 256, 0, stream>>>(wv, wvb, 4194304);
    cvt_kernel<<<4096, 256, 0, stream>>>(wo, wob, 4194304);

    qkv_gemm<<<dim3(64, 16, 3), 256, 0, stream>>>(xb, wqb, wkb, wvb, bq, bk, bv,
                                                  cosp, sinp, qo, ko, vto);
    attn_kernel<<<dim3(16, 16, 2), 256, 0, stream>>>(qo, ko, vto, ob);
    out_gemm<<<dim3(64, 16), 256, 0, stream>>>(ob, wob, out);
}

// Round 3
// 493.726 us; speedup vs baseline: 1.7757x; 1.1813x over previous
//
#include <hip/hip_runtime.h>

#define B_  2
#define NH  16
#define S_  2048
#define D_  128
#define HID 2048

typedef _Float16 half_t;
typedef _Float16 f16x8 __attribute__((ext_vector_type(8)));
typedef _Float16 f16x4_t __attribute__((ext_vector_type(4)));
typedef float f32x4 __attribute__((ext_vector_type(4)));

__device__ __forceinline__ void glds16(const half_t* g, half_t* l) {
    __builtin_amdgcn_global_load_lds(
        (const __attribute__((address_space(1))) void*)g,
        (__attribute__((address_space(3))) void*)l, 16, 0, 0);
}

// ---------------- fused fp32 -> fp16 convert (x, wq, wk, wv, wo -> contiguous ws) ----------------
__global__ __launch_bounds__(256) void cvt_all(
    const float* __restrict__ x,  const float* __restrict__ wq, const float* __restrict__ wk,
    const float* __restrict__ wv, const float* __restrict__ wo, half_t* __restrict__ dst)
{
    long i = ((long)blockIdx.x * 256 + threadIdx.x) * 4;
    const float* src; long off;
    if (i < 8388608)       { src = x;  off = i; }
    else if (i < 12582912) { src = wq; off = i - 8388608; }
    else if (i < 16777216) { src = wk; off = i - 12582912; }
    else if (i < 20971520) { src = wv; off = i - 16777216; }
    else                   { src = wo; off = i - 20971520; }
    float4 v = *(const float4*)(src + off);
    f16x4_t h;
    h[0] = (half_t)v.x; h[1] = (half_t)v.y; h[2] = (half_t)v.z; h[3] = (half_t)v.w;
    *(f16x4_t*)(dst + i) = h;
}

// ---------------- fused QKV GEMM + RoPE (m97 structure + swizzled LDS) ----------------
// 128x128 tile, BK=32, global_load_lds(16B). Wave (wm,wn): rows wm*64+mt*16, cols wn*16+nt*32.
__global__ __launch_bounds__(256, 3) void qkv_gemm(
    const half_t* __restrict__ xb,
    const half_t* __restrict__ wqb, const half_t* __restrict__ wkb, const half_t* __restrict__ wvb,
    const float* __restrict__ bq, const float* __restrict__ bk, const float* __restrict__ bv,
    const float* __restrict__ cosp, const float* __restrict__ sinp,
    half_t* __restrict__ qo, half_t* __restrict__ ko, half_t* __restrict__ vto)
{
    __shared__ __align__(16) half_t As[128 * 32];
    __shared__ __align__(16) half_t Bs[128 * 32];
    const int m0 = blockIdx.x * 128;
    const int n0 = blockIdx.y * 128;
    const int z  = blockIdx.z;
    const half_t* wb   = (z == 0) ? wqb : (z == 1) ? wkb : wvb;
    const float*  bias = (z == 0) ? bq  : (z == 1) ? bk  : bv;
    const int tid = threadIdx.x, wave = tid >> 6, lane = tid & 63;
    const int quad = lane >> 4, lrow = lane & 15;
    const int wm = wave >> 1, wn = wave & 1;

    // staging: wave w issue i covers rows w*32+i*16..+16 (1 KB); lane -> row base+(lane>>2), pos lane&3
    const int r0 = wave * 32 + (lane >> 2);
    const int r1 = r0 + 16;
    const int c0 = (((lane & 3) - (r0 >> 1)) & 3) * 8;   // source k-chunk (swizzle inverse)
    const int c1 = (((lane & 3) - (r1 >> 1)) & 3) * 8;
    const half_t* ag0 = xb + (size_t)(m0 + r0) * HID + c0;
    const half_t* ag1 = xb + (size_t)(m0 + r1) * HID + c1;
    const half_t* bg0 = wb + (size_t)(n0 + r0) * HID + c0;
    const half_t* bg1 = wb + (size_t)(n0 + r1) * HID + c1;
    half_t* al0 = &As[(wave * 32) * 32];
    half_t* al1 = &As[(wave * 32 + 16) * 32];
    half_t* bl0 = &Bs[(wave * 32) * 32];
    half_t* bl1 = &Bs[(wave * 32 + 16) * 32];

    f32x4 acc[4][4] = {};

    for (int k0 = 0; k0 < HID; k0 += 32) {
        __syncthreads();
        glds16(ag0 + k0, al0);
        glds16(ag1 + k0, al1);
        glds16(bg0 + k0, bl0);
        glds16(bg1 + k0, bl1);
        __syncthreads();
        f16x8 af[4], bf[4];
#pragma unroll
        for (int mt = 0; mt < 4; mt++) {
            const int ra = wm * 64 + mt * 16 + lrow;
            const int pa = (quad + (ra >> 1)) & 3;
            af[mt] = *(const f16x8*)&As[ra * 32 + pa * 8];
        }
#pragma unroll
        for (int nt = 0; nt < 4; nt++) {
            const int rb = wn * 16 + nt * 32 + lrow;
            const int pb = (quad + (rb >> 1)) & 3;
            bf[nt] = *(const f16x8*)&Bs[rb * 32 + pb * 8];
        }
#pragma unroll
        for (int mt = 0; mt < 4; mt++)
#pragma unroll
            for (int nt = 0; nt < 4; nt++)
                acc[mt][nt] = __builtin_amdgcn_mfma_f32_16x16x32_f16(af[mt], bf[nt], acc[mt][nt], 0, 0, 0);
    }

    const int head = blockIdx.y;
    float bs_[4];
#pragma unroll
    for (int nt = 0; nt < 4; nt++) bs_[nt] = bias[n0 + nt * 32 + wn * 16 + lrow];
#pragma unroll
    for (int mt = 0; mt < 4; mt++) {
#pragma unroll
        for (int r = 0; r < 4; r++) {
            const int m  = m0 + wm * 64 + mt * 16 + quad * 4 + r;
            const int bb = m >> 11;
            const int st = m & (S_ - 1);
            float res[4];
#pragma unroll
            for (int nt = 0; nt < 4; nt++) res[nt] = acc[mt][nt][r] + bs_[nt];
            if (z < 2) {
                const float* cr = cosp + st * D_;
                const float* sr = sinp + st * D_;
#pragma unroll
                for (int pr = 0; pr < 2; pr++) {
                    const int dlo = pr * 32 + wn * 16 + lrow;
                    float cl = cr[dlo], sl = sr[dlo], ch = cr[dlo + 64], sh = sr[dlo + 64];
                    float lo = res[pr], hi = res[pr + 2];
                    res[pr]     = lo * cl - hi * sl;
                    res[pr + 2] = hi * ch + lo * sh;
                }
                half_t* dst = (z == 0 ? qo : ko) + ((size_t)(bb * NH + head) * S_ + st) * D_;
#pragma unroll
                for (int nt = 0; nt < 4; nt++) dst[nt * 32 + wn * 16 + lrow] = (half_t)res[nt];
            } else {
                half_t* dst = vto + (size_t)(bb * NH + head) * D_ * S_ + st;
#pragma unroll
                for (int nt = 0; nt < 4; nt++) dst[(size_t)(nt * 32 + wn * 16 + lrow) * S_] = (half_t)res[nt];
            }
        }
    }
}

// ---------------- flash attention: Q-tile 64, 4 waves x 16 rows, glds staging ----------------
#define PLD 72
__global__ __launch_bounds__(256, 3) void attn_kernel(
    const half_t* __restrict__ qb, const half_t* __restrict__ kb,
    const half_t* __restrict__ vtb, half_t* __restrict__ ob)
{
    __shared__ __align__(16) half_t ks[64 * 128];    // 16 KB (row=s-col, 16 chunks of 16B, swizzled)
    __shared__ __align__(16) half_t vs[128 * 64];    // 16 KB (row=d, 8 chunks of 16B, swizzled)
    __shared__ __align__(16) half_t ps[4 * 16 * PLD];// 9 KB wave-private P
    const int head = blockIdx.y, b = blockIdx.z;
    const int bh = b * NH + head;
    const int tid = threadIdx.x, wave = tid >> 6, lane = tid & 63;
    const int quad = lane >> 4, lrow = lane & 15;
    const float scale = 0.08838834764831845f;  // 1/sqrt(128)
    const int q0 = blockIdx.x * 64 + wave * 16;

    f16x8 qf[4];
    {
        const half_t* qrow = qb + ((size_t)bh * S_ + q0 + lrow) * D_;
#pragma unroll
        for (int kc = 0; kc < 4; kc++) {
            f16x8 v = *(const f16x8*)(qrow + kc * 32 + quad * 8);
#pragma unroll
            for (int j = 0; j < 8; j++) v[j] = (half_t)((float)v[j] * scale);
            qf[kc] = v;
        }
    }

    const half_t* kbase = kb + (size_t)bh * S_ * D_;
    const half_t* vbase = vtb + (size_t)bh * D_ * S_;
    const int pbase = wave * 16 * PLD;

    float m_run[4], l_run[4];
#pragma unroll
    for (int r = 0; r < 4; r++) { m_run[r] = -1e30f; l_run[r] = 0.f; }
    f32x4 o[8] = {};

    for (int kt = 0; kt < 32; kt++) {
        __syncthreads();
#pragma unroll
        for (int i = 0; i < 4; i++) {
            const int rk = wave * 16 + i * 4 + (lane >> 4);
            const int ck = (((lane & 15) - (rk & 7)) & 15) * 8;
            glds16(kbase + (size_t)(kt * 64 + rk) * D_ + ck, &ks[(wave * 16 + i * 4) * 128]);
            const int rv = wave * 32 + i * 8 + (lane >> 3);
            const int cv = (((lane & 7) - (rv & 7)) & 7) * 8;
            glds16(vbase + (size_t)rv * S_ + kt * 64 + cv, &vs[(wave * 32 + i * 8) * 64]);
        }
        __syncthreads();

        // S = Q K^T (64-col tile)
        f32x4 s[4] = {};
#pragma unroll
        for (int nt = 0; nt < 4; nt++) {
            const int rk2 = nt * 16 + lrow;
#pragma unroll
            for (int kc = 0; kc < 4; kc++) {
                const int pk = (kc * 4 + quad + (rk2 & 7)) & 15;
                f16x8 kf = *(const f16x8*)&ks[rk2 * 128 + pk * 8];
                s[nt] = __builtin_amdgcn_mfma_f32_16x16x32_f16(qf[kc], kf, s[nt], 0, 0, 0);
            }
        }

        // online softmax + P write
        float alpha_r[4];
        bool upd = false;
#pragma unroll
        for (int r = 0; r < 4; r++) {
            float mx = fmaxf(fmaxf(s[0][r], s[1][r]), fmaxf(s[2][r], s[3][r]));
#pragma unroll
            for (int off = 1; off < 16; off <<= 1) mx = fmaxf(mx, __shfl_xor(mx, off));
            const float mnew = fmaxf(m_run[r], mx);
            alpha_r[r] = __expf(m_run[r] - mnew);
            upd = upd || (mnew != m_run[r]);
            m_run[r] = mnew;
            float p0 = __expf(s[0][r] - mnew);
            float p1 = __expf(s[1][r] - mnew);
            float p2 = __expf(s[2][r] - mnew);
            float p3 = __expf(s[3][r] - mnew);
            float rs = (p0 + p1) + (p2 + p3);
#pragma unroll
            for (int off = 1; off < 16; off <<= 1) rs += __shfl_xor(rs, off);
            l_run[r] = l_run[r] * alpha_r[r] + rs;
            const int prow = pbase + (quad * 4 + r) * PLD + lrow;
            ps[prow]      = (half_t)p0;
            ps[prow + 16] = (half_t)p1;
            ps[prow + 32] = (half_t)p2;
            ps[prow + 48] = (half_t)p3;
        }
        if (__any(upd)) {
#pragma unroll
            for (int r = 0; r < 4; r++)
#pragma unroll
                for (int dt = 0; dt < 8; dt++) o[dt][r] *= alpha_r[r];
        }

        // O += P V
#pragma unroll
        for (int kc2 = 0; kc2 < 2; kc2++) {
            f16x8 pf = *(const f16x8*)&ps[pbase + lrow * PLD + kc2 * 32 + quad * 8];
#pragma unroll
            for (int dt = 0; dt < 8; dt++) {
                const int rv2 = dt * 16 + lrow;
                const int pv = (kc2 * 4 + quad + (rv2 & 7)) & 7;
                f16x8 vf = *(const f16x8*)&vs[rv2 * 64 + pv * 8];
                o[dt] = __builtin_amdgcn_mfma_f32_16x16x32_f16(pf, vf, o[dt], 0, 0, 0);
            }
        }
    }

    float rl[4];
#pragma unroll
    for (int r = 0; r < 4; r++) rl[r] = 1.f / l_run[r];
#pragma unroll
    for (int dt = 0; dt < 8; dt++) {
        const int d = dt * 16 + lrow;
#pragma unroll
        for (int r = 0; r < 4; r++) {
            const int row = q0 + quad * 4 + r;
            ob[((size_t)b * S_ + row) * HID + head * D_ + d] = (half_t)(o[dt][r] * rl[r]);
        }
    }
}

// ---------------- output projection (same GEMM structure, fp32 out) ----------------
__global__ __launch_bounds__(256, 3) void out_gemm(
    const half_t* __restrict__ ab, const half_t* __restrict__ wob, float* __restrict__ out)
{
    __shared__ __align__(16) half_t As[128 * 32];
    __shared__ __align__(16) half_t Bs[128 * 32];
    const int m0 = blockIdx.x * 128;
    const int n0 = blockIdx.y * 128;
    const int tid = threadIdx.x, wave = tid >> 6, lane = tid & 63;
    const int quad = lane >> 4, lrow = lane & 15;
    const int wm = wave >> 1, wn = wave & 1;

    const int r0 = wave * 32 + (lane >> 2);
    const int r1 = r0 + 16;
    const int c0 = (((lane & 3) - (r0 >> 1)) & 3) * 8;
    const int c1 = (((lane & 3) - (r1 >> 1)) & 3) * 8;
    const half_t* ag0 = ab  + (size_t)(m0 + r0) * HID + c0;
    const half_t* ag1 = ab  + (size_t)(m0 + r1) * HID + c1;
    const half_t* bg0 = wob + (size_t)(n0 + r0) * HID + c0;
    const half_t* bg1 = wob + (size_t)(n0 + r1) * HID + c1;
    half_t* al0 = &As[(wave * 32) * 32];
    half_t* al1 = &As[(wave * 32 + 16) * 32];
    half_t* bl0 = &Bs[(wave * 32) * 32];
    half_t* bl1 = &Bs[(wave * 32 + 16) * 32];

    f32x4 acc[4][4] = {};

    for (int k0 = 0; k0 < HID; k0 += 32) {
        __syncthreads();
        glds16(ag0 + k0, al0);
        glds16(ag1 + k0, al1);
        glds16(bg0 + k0, bl0);
        glds16(bg1 + k0, bl1);
        __syncthreads();
        f16x8 af[4], bf[4];
#pragma unroll
        for (int mt = 0; mt < 4; mt++) {
            const int ra = wm * 64 + mt * 16 + lrow;
            const int pa = (quad + (ra >> 1)) & 3;
            af[mt] = *(const f16x8*)&As[ra * 32 + pa * 8];
        }
#pragma unroll
        for (int nt = 0; nt < 4; nt++) {
            const int rb = wn * 16 + nt * 32 + lrow;
            const int pb = (quad + (rb >> 1)) & 3;
            bf[nt] = *(const f16x8*)&Bs[rb * 32 + pb * 8];
        }
#pragma unroll
        for (int mt = 0; mt < 4; mt++)
#pragma unroll
            for (int nt = 0; nt < 4; nt++)
                acc[mt][nt] = __builtin_amdgcn_mfma_f32_16x16x32_f16(af[mt], bf[nt], acc[mt][nt], 0, 0, 0);
    }

#pragma unroll
    for (int mt = 0; mt < 4; mt++)
#pragma unroll
        for (int r = 0; r < 4; r++) {
            const int m = m0 + wm * 64 + mt * 16 + quad * 4 + r;
#pragma unroll
            for (int nt = 0; nt < 4; nt++)
                out[(size_t)m * HID + n0 + nt * 32 + wn * 16 + lrow] = acc[mt][nt][r];
        }
}

extern "C" void kernel_launch(void* const* d_in, const int* in_sizes, int n_in,
                              void* d_out, int out_size, void* d_ws, size_t ws_size,
                              hipStream_t stream)
{
    const float* x    = (const float*)d_in[0];
    const float* cosp = (const float*)d_in[1];
    const float* sinp = (const float*)d_in[2];
    const float* wq   = (const float*)d_in[3];
    const float* bq   = (const float*)d_in[4];
    const float* wk   = (const float*)d_in[5];
    const float* bk   = (const float*)d_in[6];
    const float* wv   = (const float*)d_in[7];
    const float* bv   = (const float*)d_in[8];
    const float* wo   = (const float*)d_in[9];
    float* out = (float*)d_out;

    half_t* w   = (half_t*)d_ws;
    half_t* xb  = w;                    // 8388608 (contiguous cvt dst start)
    half_t* wqb = xb  + 8388608;
    half_t* wkb = wqb + 4194304;
    half_t* wvb = wkb + 4194304;
    half_t* wob = wvb + 4194304;
    half_t* qo  = wob + 4194304;        // (b,h,s,d)
    half_t* ko  = qo  + 8388608;        // (b,h,s,d)
    half_t* vto = ko  + 8388608;        // (b,h,d,s)
    half_t* ob  = vto + 8388608;        // (b,s,h*d)

    cvt_all<<<24576, 256, 0, stream>>>(x, wq, wk, wv, wo, xb);
    qkv_gemm<<<dim3(32, 16, 3), 256, 0, stream>>>(xb, wqb, wkb, wvb, bq, bk, bv,
                                                  cosp, sinp, qo, ko, vto);
    attn_kernel<<<dim3(32, 16, 2), 256, 0, stream>>>(qo, ko, vto, ob);
    out_gemm<<<dim3(32, 16), 256, 0, stream>>>(ob, wob, out);
}

// Round 4
// 422.369 us; speedup vs baseline: 2.0756x; 1.1689x over previous
//
#include <hip/hip_runtime.h>

#define B_  2
#define NH  16
#define S_  2048
#define D_  128
#define HID 2048

typedef _Float16 half_t;
typedef _Float16 f16x8 __attribute__((ext_vector_type(8)));
typedef _Float16 f16x4_t __attribute__((ext_vector_type(4)));
typedef float f32x4 __attribute__((ext_vector_type(4)));

__device__ __forceinline__ void glds16(const half_t* g, half_t* l) {
    __builtin_amdgcn_global_load_lds(
        (const __attribute__((address_space(1))) void*)g,
        (__attribute__((address_space(3))) void*)l, 16, 0, 0);
}
__device__ __forceinline__ float fexp2(float x) { return __builtin_amdgcn_exp2f(x); }

// ---------------- fused fp32 -> fp16 convert ----------------
__global__ __launch_bounds__(256) void cvt_all(
    const float* __restrict__ x,  const float* __restrict__ wq, const float* __restrict__ wk,
    const float* __restrict__ wv, const float* __restrict__ wo, half_t* __restrict__ dst)
{
    long i = ((long)blockIdx.x * 256 + threadIdx.x) * 4;
    const float* src; long off;
    if (i < 8388608)       { src = x;  off = i; }
    else if (i < 12582912) { src = wq; off = i - 8388608; }
    else if (i < 16777216) { src = wk; off = i - 12582912; }
    else if (i < 20971520) { src = wv; off = i - 16777216; }
    else                   { src = wo; off = i - 20971520; }
    float4 v = *(const float4*)(src + off);
    f16x4_t h;
    h[0] = (half_t)v.x; h[1] = (half_t)v.y; h[2] = (half_t)v.z; h[3] = (half_t)v.w;
    *(f16x4_t*)(dst + i) = h;
}

// ---------------- fused QKV GEMM + RoPE (m97 structure + swizzled LDS) ----------------
__global__ __launch_bounds__(256, 3) void qkv_gemm(
    const half_t* __restrict__ xb,
    const half_t* __restrict__ wqb, const half_t* __restrict__ wkb, const half_t* __restrict__ wvb,
    const float* __restrict__ bq, const float* __restrict__ bk, const float* __restrict__ bv,
    const float* __restrict__ cosp, const float* __restrict__ sinp,
    half_t* __restrict__ qo, half_t* __restrict__ ko, half_t* __restrict__ vto)
{
    __shared__ __align__(16) half_t As[128 * 32];
    __shared__ __align__(16) half_t Bs[128 * 32];
    const int m0 = blockIdx.x * 128;
    const int n0 = blockIdx.y * 128;
    const int z  = blockIdx.z;
    const half_t* wb   = (z == 0) ? wqb : (z == 1) ? wkb : wvb;
    const float*  bias = (z == 0) ? bq  : (z == 1) ? bk  : bv;
    const int tid = threadIdx.x, wave = tid >> 6, lane = tid & 63;
    const int quad = lane >> 4, lrow = lane & 15;
    const int wm = wave >> 1, wn = wave & 1;

    const int r0 = wave * 32 + (lane >> 2);
    const int r1 = r0 + 16;
    const int c0 = (((lane & 3) - (r0 >> 1)) & 3) * 8;
    const int c1 = (((lane & 3) - (r1 >> 1)) & 3) * 8;
    const half_t* ag0 = xb + (size_t)(m0 + r0) * HID + c0;
    const half_t* ag1 = xb + (size_t)(m0 + r1) * HID + c1;
    const half_t* bg0 = wb + (size_t)(n0 + r0) * HID + c0;
    const half_t* bg1 = wb + (size_t)(n0 + r1) * HID + c1;
    half_t* al0 = &As[(wave * 32) * 32];
    half_t* al1 = &As[(wave * 32 + 16) * 32];
    half_t* bl0 = &Bs[(wave * 32) * 32];
    half_t* bl1 = &Bs[(wave * 32 + 16) * 32];

    f32x4 acc[4][4] = {};

    for (int k0 = 0; k0 < HID; k0 += 32) {
        __syncthreads();
        glds16(ag0 + k0, al0);
        glds16(ag1 + k0, al1);
        glds16(bg0 + k0, bl0);
        glds16(bg1 + k0, bl1);
        __syncthreads();
        f16x8 af[4], bf[4];
#pragma unroll
        for (int mt = 0; mt < 4; mt++) {
            const int ra = wm * 64 + mt * 16 + lrow;
            const int pa = (quad + (ra >> 1)) & 3;
            af[mt] = *(const f16x8*)&As[ra * 32 + pa * 8];
        }
#pragma unroll
        for (int nt = 0; nt < 4; nt++) {
            const int rb = wn * 16 + nt * 32 + lrow;
            const int pb = (quad + (rb >> 1)) & 3;
            bf[nt] = *(const f16x8*)&Bs[rb * 32 + pb * 8];
        }
#pragma unroll
        for (int mt = 0; mt < 4; mt++)
#pragma unroll
            for (int nt = 0; nt < 4; nt++)
                acc[mt][nt] = __builtin_amdgcn_mfma_f32_16x16x32_f16(af[mt], bf[nt], acc[mt][nt], 0, 0, 0);
    }

    const int head = blockIdx.y;
    float bs_[4];
#pragma unroll
    for (int nt = 0; nt < 4; nt++) bs_[nt] = bias[n0 + nt * 32 + wn * 16 + lrow];
#pragma unroll
    for (int mt = 0; mt < 4; mt++) {
#pragma unroll
        for (int r = 0; r < 4; r++) {
            const int m  = m0 + wm * 64 + mt * 16 + quad * 4 + r;
            const int bb = m >> 11;
            const int st = m & (S_ - 1);
            float res[4];
#pragma unroll
            for (int nt = 0; nt < 4; nt++) res[nt] = acc[mt][nt][r] + bs_[nt];
            if (z < 2) {
                const float* cr = cosp + st * D_;
                const float* sr = sinp + st * D_;
#pragma unroll
                for (int pr = 0; pr < 2; pr++) {
                    const int dlo = pr * 32 + wn * 16 + lrow;
                    float cl = cr[dlo], sl = sr[dlo], ch = cr[dlo + 64], sh = sr[dlo + 64];
                    float lo = res[pr], hi = res[pr + 2];
                    res[pr]     = lo * cl - hi * sl;
                    res[pr + 2] = hi * ch + lo * sh;
                }
                half_t* dst = (z == 0 ? qo : ko) + ((size_t)(bb * NH + head) * S_ + st) * D_;
#pragma unroll
                for (int nt = 0; nt < 4; nt++) dst[nt * 32 + wn * 16 + lrow] = (half_t)res[nt];
            } else {
                half_t* dst = vto + (size_t)(bb * NH + head) * D_ * S_ + st;
#pragma unroll
                for (int nt = 0; nt < 4; nt++) dst[(size_t)(nt * 32 + wn * 16 + lrow) * S_] = (half_t)res[nt];
            }
        }
    }
}

// ---------------- flash attention: Q-tile 128 (wave owns 32 rows), S^T softmax ----------------
#define PLD 72
__global__ __launch_bounds__(256, 2) void attn_kernel(
    const half_t* __restrict__ qb, const half_t* __restrict__ kb,
    const half_t* __restrict__ vtb, half_t* __restrict__ ob)
{
    __shared__ __align__(16) half_t ks[64 * 128];      // 16 KB swizzled
    __shared__ __align__(16) half_t vs[128 * 64];      // 16 KB swizzled
    __shared__ __align__(16) half_t ps[4 * 32 * PLD];  // 18 KB wave-private P (A-layout)
    const int head = blockIdx.y, b = blockIdx.z;
    const int bh = b * NH + head;
    const int tid = threadIdx.x, wave = tid >> 6, lane = tid & 63;
    const int quad = lane >> 4, lrow = lane & 15;
    // scale * log2(e): softmax computed in exp2 domain
    const float SC = 0.08838834764831845f * 1.4426950408889634f;
    const int q0 = blockIdx.x * 128 + wave * 32;

    // Q fragments, pre-scaled (used as MFMA *B* operand: B-frag(X) == A-frag(X) data)
    f16x8 qf[2][4];
#pragma unroll
    for (int mt = 0; mt < 2; mt++) {
        const half_t* qrow = qb + ((size_t)bh * S_ + q0 + mt * 16 + lrow) * D_;
#pragma unroll
        for (int kc = 0; kc < 4; kc++) {
            f16x8 v = *(const f16x8*)(qrow + kc * 32 + quad * 8);
#pragma unroll
            for (int j = 0; j < 8; j++) v[j] = (half_t)((float)v[j] * SC);
            qf[mt][kc] = v;
        }
    }

    const half_t* kbase = kb + (size_t)bh * S_ * D_;
    const half_t* vbase = vtb + (size_t)bh * D_ * S_;
    const int pbase = wave * 32 * PLD;

    float m_run[2] = {-1e30f, -1e30f}, l_run[2] = {0.f, 0.f};
    f32x4 o[2][8] = {};

    for (int kt = 0; kt < 32; kt++) {
        __syncthreads();
#pragma unroll
        for (int i = 0; i < 4; i++) {
            const int rk = wave * 16 + i * 4 + (lane >> 4);
            const int ck = (((lane & 15) - (rk & 7)) & 15) * 8;
            glds16(kbase + (size_t)(kt * 64 + rk) * D_ + ck, &ks[(wave * 16 + i * 4) * 128]);
            const int rv = wave * 32 + i * 8 + (lane >> 3);
            const int cv = (((lane & 7) - (rv & 7)) & 7) * 8;
            glds16(vbase + (size_t)rv * S_ + kt * 64 + cv, &vs[(wave * 32 + i * 8) * 64]);
        }
        __syncthreads();

        // S^T = K_tile . Q^T : lane holds q-row = lrow, k-col = nt*16+quad*4+r  (in-lane!)
        f32x4 st[2][4] = {};
#pragma unroll
        for (int nt = 0; nt < 4; nt++) {
            const int rk2 = nt * 16 + lrow;
#pragma unroll
            for (int kc = 0; kc < 4; kc++) {
                const int pk = (kc * 4 + quad + (rk2 & 7)) & 15;
                f16x8 kf = *(const f16x8*)&ks[rk2 * 128 + pk * 8];
                st[0][nt] = __builtin_amdgcn_mfma_f32_16x16x32_f16(kf, qf[0][kc], st[0][nt], 0, 0, 0);
                st[1][nt] = __builtin_amdgcn_mfma_f32_16x16x32_f16(kf, qf[1][kc], st[1][nt], 0, 0, 0);
            }
        }

        // online softmax: in-lane tree + 2 shuffles; packed b64 P stores (A-layout)
        bool upd = false;
        float alpha[2];
#pragma unroll
        for (int mt = 0; mt < 2; mt++) {
            float m01 = fmaxf(fmaxf(st[mt][0][0], st[mt][0][1]), fmaxf(st[mt][0][2], st[mt][0][3]));
            float m11 = fmaxf(fmaxf(st[mt][1][0], st[mt][1][1]), fmaxf(st[mt][1][2], st[mt][1][3]));
            float m21 = fmaxf(fmaxf(st[mt][2][0], st[mt][2][1]), fmaxf(st[mt][2][2], st[mt][2][3]));
            float m31 = fmaxf(fmaxf(st[mt][3][0], st[mt][3][1]), fmaxf(st[mt][3][2], st[mt][3][3]));
            float mx = fmaxf(fmaxf(m01, m11), fmaxf(m21, m31));
            mx = fmaxf(mx, __shfl_xor(mx, 16));
            mx = fmaxf(mx, __shfl_xor(mx, 32));
            const float mnew = fmaxf(m_run[mt], mx);
            alpha[mt] = fexp2(m_run[mt] - mnew);
            upd = upd || (mnew > m_run[mt]);
            m_run[mt] = mnew;
            float rs = 0.f;
#pragma unroll
            for (int nt = 0; nt < 4; nt++) {
                f16x4_t pk4;
#pragma unroll
                for (int r = 0; r < 4; r++) {
                    float p = fexp2(st[mt][nt][r] - mnew);
                    rs += p;
                    pk4[r] = (half_t)p;
                }
                *(f16x4_t*)&ps[pbase + (mt * 16 + lrow) * PLD + nt * 16 + quad * 4] = pk4;
            }
            rs += __shfl_xor(rs, 16);
            rs += __shfl_xor(rs, 32);
            l_run[mt] = l_run[mt] * alpha[mt] + rs;
        }
        if (__any(upd)) {
#pragma unroll
            for (int mt = 0; mt < 2; mt++) {
                float ab[4];
#pragma unroll
                for (int r = 0; r < 4; r++) ab[r] = __shfl(alpha[mt], quad * 4 + r, 16);
#pragma unroll
                for (int dt = 0; dt < 8; dt++)
#pragma unroll
                    for (int r = 0; r < 4; r++) o[mt][dt][r] *= ab[r];
            }
        }

        // O += P V
#pragma unroll
        for (int kc2 = 0; kc2 < 2; kc2++) {
            f16x8 pf0 = *(const f16x8*)&ps[pbase + lrow * PLD + kc2 * 32 + quad * 8];
            f16x8 pf1 = *(const f16x8*)&ps[pbase + (16 + lrow) * PLD + kc2 * 32 + quad * 8];
#pragma unroll
            for (int dt = 0; dt < 8; dt++) {
                const int rv2 = dt * 16 + lrow;
                const int pv = (kc2 * 4 + quad + (rv2 & 7)) & 7;
                f16x8 vf = *(const f16x8*)&vs[rv2 * 64 + pv * 8];
                o[0][dt] = __builtin_amdgcn_mfma_f32_16x16x32_f16(pf0, vf, o[0][dt], 0, 0, 0);
                o[1][dt] = __builtin_amdgcn_mfma_f32_16x16x32_f16(pf1, vf, o[1][dt], 0, 0, 0);
            }
        }
    }

    // epilogue
#pragma unroll
    for (int mt = 0; mt < 2; mt++) {
        const float rl = 1.f / l_run[mt];
        float rb[4];
#pragma unroll
        for (int r = 0; r < 4; r++) rb[r] = __shfl(rl, quad * 4 + r, 16);
#pragma unroll
        for (int dt = 0; dt < 8; dt++) {
            const int d = dt * 16 + lrow;
#pragma unroll
            for (int r = 0; r < 4; r++) {
                const int row = q0 + mt * 16 + quad * 4 + r;
                ob[((size_t)b * S_ + row) * HID + head * D_ + d] = (half_t)(o[mt][dt][r] * rb[r]);
            }
        }
    }
}

// ---------------- output projection ----------------
__global__ __launch_bounds__(256, 3) void out_gemm(
    const half_t* __restrict__ ab, const half_t* __restrict__ wob, float* __restrict__ out)
{
    __shared__ __align__(16) half_t As[128 * 32];
    __shared__ __align__(16) half_t Bs[128 * 32];
    const int m0 = blockIdx.x * 128;
    const int n0 = blockIdx.y * 128;
    const int tid = threadIdx.x, wave = tid >> 6, lane = tid & 63;
    const int quad = lane >> 4, lrow = lane & 15;
    const int wm = wave >> 1, wn = wave & 1;

    const int r0 = wave * 32 + (lane >> 2);
    const int r1 = r0 + 16;
    const int c0 = (((lane & 3) - (r0 >> 1)) & 3) * 8;
    const int c1 = (((lane & 3) - (r1 >> 1)) & 3) * 8;
    const half_t* ag0 = ab  + (size_t)(m0 + r0) * HID + c0;
    const half_t* ag1 = ab  + (size_t)(m0 + r1) * HID + c1;
    const half_t* bg0 = wob + (size_t)(n0 + r0) * HID + c0;
    const half_t* bg1 = wob + (size_t)(n0 + r1) * HID + c1;
    half_t* al0 = &As[(wave * 32) * 32];
    half_t* al1 = &As[(wave * 32 + 16) * 32];
    half_t* bl0 = &Bs[(wave * 32) * 32];
    half_t* bl1 = &Bs[(wave * 32 + 16) * 32];

    f32x4 acc[4][4] = {};

    for (int k0 = 0; k0 < HID; k0 += 32) {
        __syncthreads();
        glds16(ag0 + k0, al0);
        glds16(ag1 + k0, al1);
        glds16(bg0 + k0, bl0);
        glds16(bg1 + k0, bl1);
        __syncthreads();
        f16x8 af[4], bf[4];
#pragma unroll
        for (int mt = 0; mt < 4; mt++) {
            const int ra = wm * 64 + mt * 16 + lrow;
            const int pa = (quad + (ra >> 1)) & 3;
            af[mt] = *(const f16x8*)&As[ra * 32 + pa * 8];
        }
#pragma unroll
        for (int nt = 0; nt < 4; nt++) {
            const int rb = wn * 16 + nt * 32 + lrow;
            const int pb = (quad + (rb >> 1)) & 3;
            bf[nt] = *(const f16x8*)&Bs[rb * 32 + pb * 8];
        }
#pragma unroll
        for (int mt = 0; mt < 4; mt++)
#pragma unroll
            for (int nt = 0; nt < 4; nt++)
                acc[mt][nt] = __builtin_amdgcn_mfma_f32_16x16x32_f16(af[mt], bf[nt], acc[mt][nt], 0, 0, 0);
    }

#pragma unroll
    for (int mt = 0; mt < 4; mt++)
#pragma unroll
        for (int r = 0; r < 4; r++) {
            const int m = m0 + wm * 64 + mt * 16 + quad * 4 + r;
#pragma unroll
            for (int nt = 0; nt < 4; nt++)
                out[(size_t)m * HID + n0 + nt * 32 + wn * 16 + lrow] = acc[mt][nt][r];
        }
}

extern "C" void kernel_launch(void* const* d_in, const int* in_sizes, int n_in,
                              void* d_out, int out_size, void* d_ws, size_t ws_size,
                              hipStream_t stream)
{
    const float* x    = (const float*)d_in[0];
    const float* cosp = (const float*)d_in[1];
    const float* sinp = (const float*)d_in[2];
    const float* wq   = (const float*)d_in[3];
    const float* bq   = (const float*)d_in[4];
    const float* wk   = (const float*)d_in[5];
    const float* bk   = (const float*)d_in[6];
    const float* wv   = (const float*)d_in[7];
    const float* bv   = (const float*)d_in[8];
    const float* wo   = (const float*)d_in[9];
    float* out = (float*)d_out;

    half_t* w   = (half_t*)d_ws;
    half_t* xb  = w;
    half_t* wqb = xb  + 8388608;
    half_t* wkb = wqb + 4194304;
    half_t* wvb = wkb + 4194304;
    half_t* wob = wvb + 4194304;
    half_t* qo  = wob + 4194304;        // (b,h,s,d)
    half_t* ko  = qo  + 8388608;        // (b,h,s,d)
    half_t* vto = ko  + 8388608;        // (b,h,d,s)
    half_t* ob  = vto + 8388608;        // (b,s,h*d)

    cvt_all<<<24576, 256, 0, stream>>>(x, wq, wk, wv, wo, xb);
    qkv_gemm<<<dim3(32, 16, 3), 256, 0, stream>>>(xb, wqb, wkb, wvb, bq, bk, bv,
                                                  cosp, sinp, qo, ko, vto);
    attn_kernel<<<dim3(16, 16, 2), 256, 0, stream>>>(qo, ko, vto, ob);
    out_gemm<<<dim3(32, 16), 256, 0, stream>>>(ob, wob, out);
}